// Round 6
// baseline (4523.685 us; speedup 1.0000x reference)
//
#include <hip/hip_runtime.h>

#define BB 16
#define HH 128
#define WW 128
#define SC 60              // compact state channels (ch 4..63)
#define TPX 32             // tile width in pixels
#define NR  8              // rows per block
#define NPIX (BB*HH*WW)
#define KF 192
#define HID 256

// workspace offsets (bytes)
#define WS_WTP 0u              // 98,304  : GEMM1 B-fragments bf16
#define WS_WFP 98304u          // 32,768  : GEMM2 B-fragments bf16
#define WS_WCB 131072u         //  2,304  : conv weights bf16 [2][9][64]
#define WS_AUX 133376u         // 2,097,152: aux bf16 [NPIX][4] (ch0..3 * life)
#define WS_ST  2230528u        // 62,914,560: fp32 state [NPIX][60]

typedef __attribute__((ext_vector_type(8))) short short8;
typedef __attribute__((ext_vector_type(8))) unsigned short ushort8;
typedef __attribute__((ext_vector_type(4))) float f4;

// LDS layout (bytes):
//   xs   [4][34][66] ushort @ 0      : 17,952  (rolling 4-row halo window)
//   FcH                     @ 17,952 : 16,384  (Fc [32][128]ush swz = first 8KB;
//                                               h [32][256]ush swz = all 16KB, overlay)
//   wcvb [2][9][64]  ushort @ 34,336 :  2,304
#define OFF_FCH 17952
#define OFF_WCV 34336
#define SMEM_SZ 36640

__device__ __forceinline__ unsigned short f2b(float f) {   // fp32 -> bf16 RTNE
    unsigned x = __float_as_uint(f);
    x += 0x7fffu + ((x >> 16) & 1u);
    return (unsigned short)(x >> 16);
}
__device__ __forceinline__ float b2f(unsigned short u) {
    return __uint_as_float(((unsigned)u) << 16);
}
__device__ __forceinline__ int refl(int i, int n) {
    if (i < 0) return -i;
    if (i >= n) return 2*n - 2 - i;
    return i;
}

// prep: weights into MFMA B-fragment order (bf16). Verified layout (r4/r5).
__global__ __launch_bounds__(256) void prep(
    const float* __restrict__ wh, const float* __restrict__ wf,
    unsigned short* __restrict__ wtp, unsigned short* __restrict__ wfp)
{
    int i = blockIdx.x * 256 + threadIdx.x;   // 8192 groups
    if (i < 6144) {
        const int l = i & 63, r = i >> 6;
        const int ks = r % 6, r2 = r / 6;
        const int ot = r2 & 3, os = r2 >> 2;
        const int row = os*64 + ot*16 + (l & 15);
        const int k0  = ks*32 + (l >> 4)*8;
        ushort8 v;
        #pragma unroll
        for (int j = 0; j < 8; ++j) v[j] = f2b(wh[row*KF + k0 + j]);
        *(ushort8*)&wtp[(size_t)i * 8] = v;
    } else {
        const int g = i - 6144;               // 2048 groups
        const int l = g & 63, r = g >> 6;
        const int ks2 = r & 7, r2 = r >> 3;
        const int ct = r2 & 1, cs = r2 >> 1;
        const int c  = cs*32 + ct*16 + (l & 15);
        const int o0 = ks2*32 + (l >> 4)*8;
        ushort8 v;
        #pragma unroll
        for (int j = 0; j < 8; ++j) v[j] = f2b(wf[c*HID + o0 + j]);
        *(ushort8*)&wfp[(size_t)g * 8] = v;
    }
}

// prep2: conv weights -> bf16 [filter][tap][ch] (verified mapping r2-r5)
__global__ __launch_bounds__(256) void prep2(
    const float* __restrict__ w1, const float* __restrict__ w2,
    unsigned short* __restrict__ wcb)
{
    int i = blockIdx.x * 256 + threadIdx.x;
    if (i < 1152) {
        const int f = i / 576, rem = i - f * 576;
        const int t = rem >> 6, c = rem & 63;
        wcb[i] = f2b((f ? w2 : w1)[c*9 + t]);
    }
}

// Raw 16-channel slot load for halo staging.
template<int SRCF>
__device__ __forceinline__ void load_raw(const float* s, const unsigned short* aux,
                                         size_t pix, int q, f4* stg)
{
    if (SRCF == 0) {
        const f4* p = (const f4*)(s + pix*64 + (q<<4));
        stg[0]=p[0]; stg[1]=p[1]; stg[2]=p[2]; stg[3]=p[3];
    } else if (q == 0) {
        const float2 av = *(const float2*)(aux + pix*4);   // ch0..3 pre-bf16
        stg[0].x = av.x; stg[0].y = av.y; stg[0].z = 0.f; stg[0].w = 0.f;
        const f4* p = (const f4*)(s + pix*SC);
        stg[1]=p[0]; stg[2]=p[1]; stg[3]=p[2];
    } else {
        const f4* p = (const f4*)(s + pix*SC + (q<<4) - 4);
        stg[0]=p[0]; stg[1]=p[1]; stg[2]=p[2]; stg[3]=p[3];
    }
}

template<int SRCF>
__device__ __forceinline__ void cvt_write(const f4* stg, int q, unsigned short* dp)
{
    ushort8 o0, o1;
    if (SRCF == 1 && q == 0) {
        const unsigned ax = __float_as_uint(stg[0].x), ay = __float_as_uint(stg[0].y);
        o0[0]=(unsigned short)(ax & 0xffff); o0[1]=(unsigned short)(ax >> 16);
        o0[2]=(unsigned short)(ay & 0xffff); o0[3]=(unsigned short)(ay >> 16);
        o0[4]=f2b(stg[1].x); o0[5]=f2b(stg[1].y); o0[6]=f2b(stg[1].z); o0[7]=f2b(stg[1].w);
        o1[0]=f2b(stg[2].x); o1[1]=f2b(stg[2].y); o1[2]=f2b(stg[2].z); o1[3]=f2b(stg[2].w);
        o1[4]=f2b(stg[3].x); o1[5]=f2b(stg[3].y); o1[6]=f2b(stg[3].z); o1[7]=f2b(stg[3].w);
    } else {
        o0[0]=f2b(stg[0].x); o0[1]=f2b(stg[0].y); o0[2]=f2b(stg[0].z); o0[3]=f2b(stg[0].w);
        o0[4]=f2b(stg[1].x); o0[5]=f2b(stg[1].y); o0[6]=f2b(stg[1].z); o0[7]=f2b(stg[1].w);
        o1[0]=f2b(stg[2].x); o1[1]=f2b(stg[2].y); o1[2]=f2b(stg[2].z); o1[3]=f2b(stg[2].w);
        o1[4]=f2b(stg[3].x); o1[5]=f2b(stg[3].y); o1[6]=f2b(stg[3].z); o1[7]=f2b(stg[3].w);
    }
    *(ushort8*)dp       = o0;
    *(ushort8*)(dp + 8) = o1;
}

// SRCF: 0 = src is xin (64ch fp32 raw), 1 = src is state60 + aux
// DSTF: 0 = dst is state60 (+ write aux if SRCF==0), 1 = dst is out (64ch fp32)
template<int SRCF, int DSTF>
__global__ __launch_bounds__(256, 4) void nca_step(
    const float* __restrict__ src, unsigned short* __restrict__ aux,
    float* __restrict__ dst,
    const unsigned short* __restrict__ wtp, const unsigned short* __restrict__ wfp,
    const unsigned short* __restrict__ wcbg,
    const float* __restrict__ bh, const float* __restrict__ rnd)
{
    __shared__ __align__(16) char smem[SMEM_SZ];
    unsigned short* xs   = (unsigned short*)smem;
    char*           fch  = smem + OFF_FCH;
    unsigned short* wcvb = (unsigned short*)(smem + OFF_WCV);

    const int tid = threadIdx.x;
    // decode: XCD x owns rows [x*16,(x+1)*16) of every batch (slab locality across steps)
    const int d  = blockIdx.x;
    const int x  = d & 7;
    const int ii = d >> 3;
    const int wt = ii & 3, sl = (ii >> 2) & 1, b = ii >> 3;
    const int h0 = (x*2 + sl) * NR;
    const int w0 = wt * TPX;

    for (int j = tid; j < 144; j += 256)
        ((ushort8*)wcvb)[j] = ((const ushort8*)wcbg)[j];

    // prologue: rows h0-1..h0+1 -> LDS slots 3,0,1
    for (int t = tid; t < 408; t += 256) {
        const int rr = t / 136, s2 = t - rr*136;
        const int px = s2 >> 2, q = s2 & 3;
        const int hr = refl(h0 - 1 + rr, HH);
        const int sc = refl(w0 - 1 + px, WW);
        const size_t pix = ((size_t)b*HH + hr)*WW + sc;
        f4 pst[4];
        load_raw<SRCF>(src, aux, pix, q, pst);
        cvt_write<SRCF>(pst, q, xs + (((rr+3)&3)*34 + px)*66 + q*16);
    }
    // row h0+2 -> regs (pipeline register state)
    f4 stg[4];
    const int ppx = tid >> 2, pq = tid & 3;
    const int psc = refl(w0 - 1 + ppx, WW);
    if (tid < 136)
        load_raw<SRCF>(src, aux, ((size_t)b*HH + refl(h0+2, HH))*WW + psc, pq, stg);

    const int l = tid & 63, wv = tid >> 6;
    const int lr = l & 15, gq = l >> 4;
    const int os = wv;
    const int mt2 = wv >> 1, cs = wv & 1;

    float bias[4];
    #pragma unroll
    for (int ot = 0; ot < 4; ++ot) bias[ot] = bh[os*64 + ot*16 + lr];

    __syncthreads();

    #pragma unroll 1
    for (int r = 0; r < NR; ++r) {
        // 1. ds_write row r+2 into slot (r+2)&3 (rows 2..8)
        if (r <= 6 && tid < 136)
            cvt_write<SRCF>(stg, pq, xs + (((r+2)&3)*34 + ppx)*66 + pq*16);
        // 2. issue loads row r+3 -> regs (rows 3..8)
        if (r <= 5 && tid < 136)
            load_raw<SRCF>(src, aux, ((size_t)b*HH + refl(h0+r+3, HH))*WW + psc, pq, stg);
        // 3. epilogue prefetch for current row h0+r (L2-warm, used ~2000cy later)
        const size_t rowbase = ((size_t)b*HH + (h0 + r))*WW + w0;
        float bse[8], lf[4], gg[4];
        #pragma unroll
        for (int r2 = 0; r2 < 4; ++r2) {
            const size_t pix = rowbase + mt2*16 + gq*4 + r2;
            if (SRCF == 0) lf[r2] = (src[pix*64] > 0.f) ? 1.f : 0.f;
            else           lf[r2] = (b2f(aux[pix*4]) > 0.f) ? 1.f : 0.f;
            gg[r2] = (rnd[pix] > 0.5f) ? 1.f : 0.f;
            #pragma unroll
            for (int ct = 0; ct < 2; ++ct) {
                const int c = cs*32 + ct*16 + lr;
                float v;
                if (SRCF == 0)   v = src[pix*64 + c];
                else if (c >= 4) v = src[pix*SC + (c-4)];
                else             v = b2f(aux[pix*4 + c]);
                bse[ct*4 + r2] = v;
            }
        }
        // 4. conv (rows r-1,r,r+1) -> Fc (swizzled)
        {
            const int cpx = tid >> 3, cg = (tid & 7) * 8;
            float a1[8], a2[8];
            #pragma unroll
            for (int k = 0; k < 8; ++k) { a1[k] = 0.f; a2[k] = 0.f; }
            #pragma unroll
            for (int t = 0; t < 9; ++t) {             // t = i2*3 + j
                const int i2 = t / 3, j = t - 3*i2;
                const ushort8 xv  = *(const ushort8*)(xs + (((r-1+j)&3)*34 + cpx + i2)*66 + cg);
                const ushort8 wv1 = *(const ushort8*)(wcvb + t*64 + cg);
                const ushort8 wv2 = *(const ushort8*)(wcvb + 576 + t*64 + cg);
                #pragma unroll
                for (int k = 0; k < 8; ++k) {
                    const float xf = b2f(xv[k]);
                    a1[k] = fmaf(xf, b2f(wv1[k]), a1[k]);
                    a2[k] = fmaf(xf, b2f(wv2[k]), a2[k]);
                }
            }
            ushort8 o1v, o2v;
            #pragma unroll
            for (int k = 0; k < 8; ++k) { o1v[k] = f2b(a1[k]); o2v[k] = f2b(a2[k]); }
            const int sw = (cpx & 7) << 4;
            *(ushort8*)(fch + ((cpx*256 + cg*2) ^ sw))       = o1v;
            *(ushort8*)(fch + ((cpx*256 + 128 + cg*2) ^ sw)) = o2v;
        }
        __syncthreads();                               // B1: Fc + row r+2 ready

        // 5. GEMM1 h = relu(F.Wh^T + b); wave = o-slice, tile 2Mt x 4Ot
        f4 acc[2][4];
        #pragma unroll
        for (int ot = 0; ot < 4; ++ot) {
            const f4 bv = {bias[ot], bias[ot], bias[ot], bias[ot]};
            acc[0][ot] = bv; acc[1][ot] = bv;
        }
        #pragma unroll
        for (int ks = 0; ks < 6; ++ks) {
            short8 afr[2];
            #pragma unroll
            for (int mt = 0; mt < 2; ++mt) {
                const int px = mt*16 + lr;
                if (ks < 2)    // x-features from halo center row (slot r&3)
                    afr[mt] = *(const short8*)(xs + ((r&3)*34 + px + 1)*66 + ks*32 + gq*8);
                else
                    afr[mt] = *(const short8*)(fch +
                                ((px*256 + (ks-2)*64 + gq*16) ^ ((px & 7) << 4)));
            }
            #pragma unroll
            for (int ot = 0; ot < 4; ++ot) {
                const short8 bfr = *(const short8*)(wtp + ((((os*4+ot)*6 + ks)*64 + l) << 3));
                acc[0][ot] = __builtin_amdgcn_mfma_f32_16x16x32_bf16(afr[0], bfr, acc[0][ot], 0,0,0);
                acc[1][ot] = __builtin_amdgcn_mfma_f32_16x16x32_bf16(afr[1], bfr, acc[1][ot], 0,0,0);
            }
        }
        __syncthreads();                               // B2: Fc reads done

        // 6. relu + bf16 h -> LDS (overlay FcH), swizzled 512B rows
        #pragma unroll
        for (int mt = 0; mt < 2; ++mt)
          #pragma unroll
          for (int ot = 0; ot < 4; ++ot)
            #pragma unroll
            for (int r2 = 0; r2 < 4; ++r2) {
                const int px = mt*16 + gq*4 + r2;
                const int o  = os*64 + ot*16 + lr;
                *(unsigned short*)(fch + ((px*512 + o*2) ^ ((px & 7) << 4))) =
                    f2b(fmaxf(acc[mt][ot][r2], 0.f));
            }
        __syncthreads();                               // B3: h ready

        // 7. ha loads
        short8 ha[8];
        #pragma unroll
        for (int ks2 = 0; ks2 < 8; ++ks2) {
            const int px = mt2*16 + lr;
            ha[ks2] = *(const short8*)(fch + ((px*512 + ks2*64 + gq*16) ^ ((px & 7) << 4)));
        }
        __syncthreads();                               // B4: h reads done (region free)

        // 8. GEMM2 + epilogue (direct scattered stores, round-3-proven profile)
        f4 acc2[2] = {{0.f,0.f,0.f,0.f},{0.f,0.f,0.f,0.f}};
        #pragma unroll
        for (int ks2 = 0; ks2 < 8; ++ks2) {
            #pragma unroll
            for (int ct = 0; ct < 2; ++ct) {
                const short8 bw = *(const short8*)(wfp + ((((cs*2+ct)*8 + ks2)*64 + l) << 3));
                acc2[ct] = __builtin_amdgcn_mfma_f32_16x16x32_bf16(ha[ks2], bw, acc2[ct], 0,0,0);
            }
        }
        #pragma unroll
        for (int ct = 0; ct < 2; ++ct)
          #pragma unroll
          for (int r2 = 0; r2 < 4; ++r2) {
            const int c = cs*32 + ct*16 + lr;
            const size_t pix = rowbase + mt2*16 + gq*4 + r2;
            const float base = bse[ct*4 + r2];
            float outv;
            if (c >= 4) outv = (base + acc2[ct][r2] * gg[r2]) * lf[r2];
            else        outv = base * lf[r2];
            if (DSTF == 1)   dst[pix*64 + c] = outv;
            else if (c >= 4) dst[pix*SC + (c-4)] = outv;
            if (SRCF == 0 && DSTF == 0 && c < 4)
                aux[pix*4 + c] = f2b(outv);            // constant across steps
          }
    }
}

extern "C" void kernel_launch(void* const* d_in, const int* in_sizes, int n_in,
                              void* d_out, int out_size, void* d_ws, size_t ws_size,
                              hipStream_t stream) {
    const float* xin = (const float*)d_in[0];
    const float* w1  = (const float*)d_in[1];
    const float* w2  = (const float*)d_in[2];
    const float* wh  = (const float*)d_in[3];
    const float* bh  = (const float*)d_in[4];
    const float* wf  = (const float*)d_in[5];
    const float* rv  = (const float*)d_in[6];

    unsigned short* wtp = (unsigned short*)((char*)d_ws + WS_WTP);
    unsigned short* wfp = (unsigned short*)((char*)d_ws + WS_WFP);
    unsigned short* wcb = (unsigned short*)((char*)d_ws + WS_WCB);
    unsigned short* aux = (unsigned short*)((char*)d_ws + WS_AUX);
    float* st = (float*)((char*)d_ws + WS_ST);
    float* om = (float*)d_out;     // 60ch scratch during s1..s6; 64ch final at s7

    prep <<<dim3(32), dim3(256), 0, stream>>>(wh, wf, wtp, wfp);
    prep2<<<dim3(5),  dim3(256), 0, stream>>>(w1, w2, wcb);

    dim3 g(1024), blk(256);
    nca_step<0,0><<<g, blk, 0, stream>>>(xin, aux, st, wtp, wfp, wcb, bh, rv);
    for (int s = 1; s < 7; ++s) {
        const float* sp = (s & 1) ? st : om;
        float* dp       = (s & 1) ? om : st;
        nca_step<1,0><<<g, blk, 0, stream>>>(sp, aux, dp, wtp, wfp, wcb, bh,
                                             rv + (size_t)s * NPIX);
    }
    nca_step<1,1><<<g, blk, 0, stream>>>(st, aux, om, wtp, wfp, wcb, bh,
                                         rv + (size_t)7 * NPIX);
}

// Round 7
// 1521.236 us; speedup vs baseline: 2.9737x; 2.9737x over previous
//
#include <hip/hip_runtime.h>

#define BB 16
#define HH 128
#define WW 128
#define SC 60              // compact state channels (ch 4..63)
#define TPX 32             // tile width in pixels
#define NPIX (BB*HH*WW)
#define KF 192
#define HID 256

// workspace offsets (bytes)
#define WS_WTP 0u              // 98,304  : GEMM1 B-fragments bf16
#define WS_WFP 98304u          // 32,768  : GEMM2 B-fragments bf16
#define WS_WCB 131072u         //  2,304  : conv weights bf16 [2][9][64]
#define WS_AUX 133376u         // 2,097,152: aux bf16 [NPIX][4] (ch0..3 * life)
#define WS_ST  2230528u        // 62,914,560: fp32 state [NPIX][60]

typedef __attribute__((ext_vector_type(8))) short short8;
typedef __attribute__((ext_vector_type(8))) unsigned short ushort8;
typedef __attribute__((ext_vector_type(4))) float f4;

// LDS layout (bytes):
//   xs   [3][34][66] ushort @ 0      : 13,464
//   h    [32][256]   ushort @ 0      : 16,384  (overlays xs after B3)
//   Fc   [32][128]   ushort @ 16,384 :  8,192  (XOR-swizzled rows)
//   basev[32][60]    float  @ 16,384 :  7,680  (overlays Fc after B3)
//   wcvb [2][9][64]  ushort @ 24,576 :  2,304
//   lgs  [64]        float  @ 26,880 :    256
#define OFF_FC  16384
#define OFF_WCV 24576
#define OFF_LG  26880
#define SMEM_SZ 27136

__device__ __forceinline__ unsigned short f2b(float f) {   // fp32 -> bf16 RTNE
    unsigned x = __float_as_uint(f);
    x += 0x7fffu + ((x >> 16) & 1u);
    return (unsigned short)(x >> 16);
}
__device__ __forceinline__ float b2f(unsigned short u) {
    return __uint_as_float(((unsigned)u) << 16);
}
__device__ __forceinline__ int refl(int i, int n) {
    if (i < 0) return -i;
    if (i >= n) return 2*n - 2 - i;
    return i;
}

// prep: weights into MFMA B-fragment order (bf16). Verified layout (r4-r6).
__global__ __launch_bounds__(256) void prep(
    const float* __restrict__ wh, const float* __restrict__ wf,
    unsigned short* __restrict__ wtp, unsigned short* __restrict__ wfp)
{
    int i = blockIdx.x * 256 + threadIdx.x;   // 8192 groups
    if (i < 6144) {
        const int l = i & 63, r = i >> 6;
        const int ks = r % 6, r2 = r / 6;
        const int ot = r2 & 3, os = r2 >> 2;
        const int row = os*64 + ot*16 + (l & 15);
        const int k0  = ks*32 + (l >> 4)*8;
        ushort8 v;
        #pragma unroll
        for (int j = 0; j < 8; ++j) v[j] = f2b(wh[row*KF + k0 + j]);
        *(ushort8*)&wtp[(size_t)i * 8] = v;
    } else {
        const int g = i - 6144;               // 2048 groups
        const int l = g & 63, r = g >> 6;
        const int ks2 = r & 7, r2 = r >> 3;
        const int ct = r2 & 1, cs = r2 >> 1;
        const int c  = cs*32 + ct*16 + (l & 15);
        const int o0 = ks2*32 + (l >> 4)*8;
        ushort8 v;
        #pragma unroll
        for (int j = 0; j < 8; ++j) v[j] = f2b(wf[c*HID + o0 + j]);
        *(ushort8*)&wfp[(size_t)g * 8] = v;
    }
}

// prep2: conv weights -> bf16 [filter][tap][ch] (verified mapping r2-r6)
__global__ __launch_bounds__(256) void prep2(
    const float* __restrict__ w1, const float* __restrict__ w2,
    unsigned short* __restrict__ wcb)
{
    int i = blockIdx.x * 256 + threadIdx.x;
    if (i < 1152) {
        const int f = i / 576, rem = i - f * 576;
        const int t = rem >> 6, c = rem & 63;
        wcb[i] = f2b((f ? w2 : w1)[c*9 + t]);
    }
}

template<int SRCF>
__device__ __forceinline__ void load_raw(const float* s, const unsigned short* aux,
                                         size_t pix, int q, f4* stg)
{
    if (SRCF == 0) {
        const f4* p = (const f4*)(s + pix*64 + (q<<4));
        stg[0]=p[0]; stg[1]=p[1]; stg[2]=p[2]; stg[3]=p[3];
    } else if (q == 0) {
        const float2 av = *(const float2*)(aux + pix*4);   // ch0..3 pre-bf16
        stg[0].x = av.x; stg[0].y = av.y; stg[0].z = 0.f; stg[0].w = 0.f;
        const f4* p = (const f4*)(s + pix*SC);
        stg[1]=p[0]; stg[2]=p[1]; stg[3]=p[2];
    } else {
        const f4* p = (const f4*)(s + pix*SC + (q<<4) - 4);
        stg[0]=p[0]; stg[1]=p[1]; stg[2]=p[2]; stg[3]=p[3];
    }
}

template<int SRCF>
__device__ __forceinline__ void cvt_write(const f4* stg, int q, unsigned short* dp)
{
    ushort8 o0, o1;
    if (SRCF == 1 && q == 0) {
        const unsigned ax = __float_as_uint(stg[0].x), ay = __float_as_uint(stg[0].y);
        o0[0]=(unsigned short)(ax & 0xffff); o0[1]=(unsigned short)(ax >> 16);
        o0[2]=(unsigned short)(ay & 0xffff); o0[3]=(unsigned short)(ay >> 16);
        o0[4]=f2b(stg[1].x); o0[5]=f2b(stg[1].y); o0[6]=f2b(stg[1].z); o0[7]=f2b(stg[1].w);
        o1[0]=f2b(stg[2].x); o1[1]=f2b(stg[2].y); o1[2]=f2b(stg[2].z); o1[3]=f2b(stg[2].w);
        o1[4]=f2b(stg[3].x); o1[5]=f2b(stg[3].y); o1[6]=f2b(stg[3].z); o1[7]=f2b(stg[3].w);
    } else {
        o0[0]=f2b(stg[0].x); o0[1]=f2b(stg[0].y); o0[2]=f2b(stg[0].z); o0[3]=f2b(stg[0].w);
        o0[4]=f2b(stg[1].x); o0[5]=f2b(stg[1].y); o0[6]=f2b(stg[1].z); o0[7]=f2b(stg[1].w);
        o1[0]=f2b(stg[2].x); o1[1]=f2b(stg[2].y); o1[2]=f2b(stg[2].z); o1[3]=f2b(stg[2].w);
        o1[4]=f2b(stg[3].x); o1[5]=f2b(stg[3].y); o1[6]=f2b(stg[3].z); o1[7]=f2b(stg[3].w);
    }
    *(ushort8*)dp       = o0;
    *(ushort8*)(dp + 8) = o1;
}

// SRCF: 0 = src is xin (64ch fp32 raw), 1 = src is state60 + aux
// DSTF: 0 = dst is state60 (+ write aux if SRCF==0), 1 = dst is out (64ch fp32)
template<int SRCF, int DSTF>
__global__ __launch_bounds__(256, 6) void nca_step(
    const float* __restrict__ src, unsigned short* __restrict__ aux,
    float* __restrict__ dst,
    const unsigned short* __restrict__ wtp, const unsigned short* __restrict__ wfp,
    const unsigned short* __restrict__ wcbg,
    const float* __restrict__ bh, const float* __restrict__ rnd)
{
    __shared__ __align__(16) char smem[SMEM_SZ];
    unsigned short* xs   = (unsigned short*)smem;
    char*           fch  = smem + OFF_FC;
    unsigned short* wcvb = (unsigned short*)(smem + OFF_WCV);
    float*          lgs  = (float*)(smem + OFF_LG);

    const int tid = threadIdx.x;
    // XCD slab decode (r5): XCD x owns rows [x*256,(x+1)*256)
    const int d  = blockIdx.x;
    const int ii = d >> 3;
    const int R  = (d & 7) * 256 + (ii >> 2);   // global row index b*128+h
    const int w0 = (ii & 3) * TPX;
    const int h  = R & 127;
    const int b  = R >> 7;

    // ---- phase 1: conv weights (L2), life/gate, halo -> bf16 LDS ----
    for (int j = tid; j < 144; j += 256)
        ((ushort8*)wcvb)[j] = ((const ushort8*)wcbg)[j];
    if (tid < TPX) {
        const size_t pix = (size_t)R * WW + w0 + tid;
        float lf;
        if (SRCF == 0) lf = (src[pix*64] > 0.f) ? 1.f : 0.f;
        else           lf = (b2f(aux[pix*4]) > 0.f) ? 1.f : 0.f;
        lgs[tid]       = lf;
        lgs[TPX + tid] = (rnd[pix] > 0.5f) ? 1.f : 0.f;
    }
    const int q = tid & 3;
    f4 breg[4];                    // fp32 center-row base (kept through GEMM1)
    int bpx = -1;
    for (int s0 = tid >> 2; s0 < 102; s0 += 64) {
        const int r3 = s0 / 34, wi = s0 - r3*34;
        const int sr = refl(h - 1 + r3, HH);
        const int sc = refl(w0 - 1 + wi, WW);
        const size_t pix = ((size_t)b*HH + sr)*WW + sc;
        f4 pst[4];
        load_raw<SRCF>(src, aux, pix, q, pst);
        cvt_write<SRCF>(pst, q, xs + (r3*34 + wi)*66 + q*16);
        if (r3 == 1 && wi >= 1 && wi <= 32) {
            bpx = wi - 1;
            breg[0]=pst[0]; breg[1]=pst[1]; breg[2]=pst[2]; breg[3]=pst[3];
        }
    }
    __syncthreads();                                          // B1

    // ---- phase 2: conv features -> Fc (swizzled) ----
    {
        const int px = tid >> 3, cg = (tid & 7) * 8;
        float a1[8], a2[8];
        #pragma unroll
        for (int k = 0; k < 8; ++k) { a1[k] = 0.f; a2[k] = 0.f; }
        #pragma unroll
        for (int t = 0; t < 9; ++t) {             // t = i2*3 + j
            const int i2 = t / 3, j = t - 3*i2;
            const ushort8 xv  = *(const ushort8*)(xs + (j*34 + px + i2)*66 + cg);
            const ushort8 wv1 = *(const ushort8*)(wcvb + t*64 + cg);
            const ushort8 wv2 = *(const ushort8*)(wcvb + 576 + t*64 + cg);
            #pragma unroll
            for (int k = 0; k < 8; ++k) {
                const float xf = b2f(xv[k]);
                a1[k] = fmaf(xf, b2f(wv1[k]), a1[k]);
                a2[k] = fmaf(xf, b2f(wv2[k]), a2[k]);
            }
        }
        ushort8 o1v, o2v;
        #pragma unroll
        for (int k = 0; k < 8; ++k) { o1v[k] = f2b(a1[k]); o2v[k] = f2b(a2[k]); }
        const int sw = (px & 7) << 4;
        *(ushort8*)(fch + ((px*256 + cg*2) ^ sw))       = o1v;
        *(ushort8*)(fch + ((px*256 + 128 + cg*2) ^ sw)) = o2v;
    }
    __syncthreads();                                          // B2

    // ---- phase 3: GEMM1 h = relu(F . Wh^T + b); wave = o-slice, tile 2Mt x 4Ot ----
    const int l = tid & 63, wv = tid >> 6;
    const int lr = l & 15, gq = l >> 4;
    const int os = wv;

    f4 acc[2][4];
    #pragma unroll
    for (int ot = 0; ot < 4; ++ot) {
        const float bv = bh[os*64 + ot*16 + lr];
        const f4 bvv = {bv, bv, bv, bv};
        acc[0][ot] = bvv; acc[1][ot] = bvv;
    }
    #pragma unroll
    for (int ks = 0; ks < 6; ++ks) {
        short8 afr[2];
        #pragma unroll
        for (int mt = 0; mt < 2; ++mt) {
            const int px = mt*16 + lr;
            if (ks < 2)    // x-features from halo center row
                afr[mt] = *(const short8*)(xs + (34 + px + 1)*66 + ks*32 + gq*8);
            else
                afr[mt] = *(const short8*)(fch +
                            ((px*256 + (ks-2)*64 + gq*16) ^ ((px & 7) << 4)));
        }
        #pragma unroll
        for (int ot = 0; ot < 4; ++ot) {
            const short8 bfr = *(const short8*)(wtp + ((((os*4 + ot)*6 + ks)*64 + l) << 3));
            acc[0][ot] = __builtin_amdgcn_mfma_f32_16x16x32_bf16(afr[0], bfr, acc[0][ot], 0,0,0);
            acc[1][ot] = __builtin_amdgcn_mfma_f32_16x16x32_bf16(afr[1], bfr, acc[1][ot], 0,0,0);
        }
    }
    __syncthreads();                                          // B3 (xs/Fc reads done)

    // h (bf16, swizzled 512B rows) overlays xs; basev (fp32) overlays Fc
    #pragma unroll
    for (int mt = 0; mt < 2; ++mt)
      #pragma unroll
      for (int ot = 0; ot < 4; ++ot)
        #pragma unroll
        for (int r2 = 0; r2 < 4; ++r2) {
            const int px = mt*16 + gq*4 + r2;
            const int o  = os*64 + ot*16 + lr;
            *(unsigned short*)(smem + ((px*512 + o*2) ^ ((px & 7) << 4))) =
                f2b(fmaxf(acc[mt][ot][r2], 0.f));
        }
    if (bpx >= 0) {
        float* bv = (float*)(smem + OFF_FC) + bpx*60;   // [c-4] indexed
        if (q == 0) {
            *(f4*)(bv + 0) = breg[1]; *(f4*)(bv + 4) = breg[2]; *(f4*)(bv + 8) = breg[3];
        } else {
            float* p = bv + q*16 - 4;
            *(f4*)(p + 0) = breg[0]; *(f4*)(p + 4) = breg[1];
            *(f4*)(p + 8) = breg[2]; *(f4*)(p + 12) = breg[3];
        }
    }
    __syncthreads();                                          // B4

    // ---- phase 4: GEMM2 dx = h . wf^T; wave = (px-half, c-half), tile 1x2 ----
    const int mt2 = wv >> 1, cs = wv & 1;
    short8 ha[8];
    #pragma unroll
    for (int ks2 = 0; ks2 < 8; ++ks2) {
        const int px = mt2*16 + lr;
        ha[ks2] = *(const short8*)(smem + ((px*512 + ks2*64 + gq*16) ^ ((px & 7) << 4)));
    }
    f4 acc2[2] = {{0.f,0.f,0.f,0.f},{0.f,0.f,0.f,0.f}};
    #pragma unroll
    for (int ks2 = 0; ks2 < 8; ++ks2) {
        #pragma unroll
        for (int ct = 0; ct < 2; ++ct) {
            const short8 bw = *(const short8*)(wfp + ((((cs*2 + ct)*8 + ks2)*64 + l) << 3));
            acc2[ct] = __builtin_amdgcn_mfma_f32_16x16x32_bf16(ha[ks2], bw, acc2[ct], 0,0,0);
        }
    }

    // ---- epilogue: gate + mask + life; direct scattered stores (r3 profile) ----
    const float* basev = (const float*)(smem + OFF_FC);
    #pragma unroll
    for (int ct = 0; ct < 2; ++ct)
      #pragma unroll
      for (int r2 = 0; r2 < 4; ++r2) {
        const int px = mt2*16 + gq*4 + r2;
        const int c  = cs*32 + ct*16 + lr;
        const size_t pix = (size_t)R * WW + w0 + px;
        const float life = lgs[px], g = lgs[TPX + px];
        float outv;
        if (c >= 4) {
            const float base = basev[px*60 + (c-4)];
            outv = (base + acc2[ct][r2] * g) * life;
        } else {
            float base = 0.f;
            if (DSTF == 1)      base = b2f(aux[pix*4 + c]);   // final step only
            else if (SRCF == 0) base = src[pix*64 + c];       // step 0 aux init
            outv = base * life;
        }
        if (DSTF == 1)   dst[pix*64 + c] = outv;
        else if (c >= 4) dst[pix*SC + (c-4)] = outv;
        if (SRCF == 0 && DSTF == 0 && c < 4)
            aux[pix*4 + c] = f2b(outv);                       // constant across steps
      }
}

extern "C" void kernel_launch(void* const* d_in, const int* in_sizes, int n_in,
                              void* d_out, int out_size, void* d_ws, size_t ws_size,
                              hipStream_t stream) {
    const float* xin = (const float*)d_in[0];
    const float* w1  = (const float*)d_in[1];
    const float* w2  = (const float*)d_in[2];
    const float* wh  = (const float*)d_in[3];
    const float* bh  = (const float*)d_in[4];
    const float* wf  = (const float*)d_in[5];
    const float* rv  = (const float*)d_in[6];

    unsigned short* wtp = (unsigned short*)((char*)d_ws + WS_WTP);
    unsigned short* wfp = (unsigned short*)((char*)d_ws + WS_WFP);
    unsigned short* wcb = (unsigned short*)((char*)d_ws + WS_WCB);
    unsigned short* aux = (unsigned short*)((char*)d_ws + WS_AUX);
    float* st = (float*)((char*)d_ws + WS_ST);
    float* om = (float*)d_out;     // 60ch scratch during s1..s6; 64ch final at s7

    prep <<<dim3(32), dim3(256), 0, stream>>>(wh, wf, wtp, wfp);
    prep2<<<dim3(5),  dim3(256), 0, stream>>>(w1, w2, wcb);

    dim3 g(8192), blk(256);
    nca_step<0,0><<<g, blk, 0, stream>>>(xin, aux, st, wtp, wfp, wcb, bh, rv);
    for (int s = 1; s < 7; ++s) {
        const float* sp = (s & 1) ? st : om;
        float* dp       = (s & 1) ? om : st;
        nca_step<1,0><<<g, blk, 0, stream>>>(sp, aux, dp, wtp, wfp, wcb, bh,
                                             rv + (size_t)s * NPIX);
    }
    nca_step<1,1><<<g, blk, 0, stream>>>(st, aux, om, wtp, wfp, wcb, bh,
                                         rv + (size_t)7 * NPIX);
}

// Round 9
// 1092.329 us; speedup vs baseline: 4.1413x; 1.3927x over previous
//
#include <hip/hip_runtime.h>

#define BB 16
#define HH 128
#define WW 128
#define SC 60              // compact state channels (ch 4..63), bf16
#define TPX 32             // tile width in pixels
#define NPIX (BB*HH*WW)
#define KF 192
#define HID 256
#define XSW 68             // xs row stride (shorts): 8B-aligned rows

// workspace offsets (bytes)
#define WS_WTP 0u              // 98,304  : GEMM1 B-fragments bf16
#define WS_WFP 98304u          // 32,768  : GEMM2 B-fragments bf16
#define WS_WCB 131072u         //  2,304  : conv weights bf16 [2][9][64]
#define WS_AUX 133376u         // 2,097,152: aux bf16 [NPIX][4] (ch0..3 * life)
#define WS_ST  2230528u        // 31,457,280: bf16 state [NPIX][60]

typedef __attribute__((ext_vector_type(8))) short short8;
typedef __attribute__((ext_vector_type(8))) unsigned short ushort8;
typedef __attribute__((ext_vector_type(4))) unsigned short us4;
typedef __attribute__((ext_vector_type(4))) float f4;

// LDS layout (bytes):
//   xs   [3][34][68] ushort @ 0      : 13,872
//   h    [32][256]   ushort @ 0      : 16,384 (overlays xs after B3)
//   stage                   @ 0      : bf16 [32][60] 3,840 / fp32 [32][64] 8,192
//   Fc   [32][128]   ushort @ 16,384 :  8,192 (XOR-swizzled rows)
//   wcvb [2][9][64]  ushort @ 24,576 :  2,304
//   lgs  [64]        float  @ 26,880 :    256
#define OFF_FC  16384
#define OFF_WCV 24576
#define OFF_LG  26880
#define SMEM_SZ 27136

__device__ __forceinline__ unsigned short f2b(float f) {   // fp32 -> bf16 RTNE
    unsigned x = __float_as_uint(f);
    x += 0x7fffu + ((x >> 16) & 1u);
    return (unsigned short)(x >> 16);
}
__device__ __forceinline__ float b2f(unsigned short u) {
    return __uint_as_float(((unsigned)u) << 16);
}
__device__ __forceinline__ int refl(int i, int n) {
    if (i < 0) return -i;
    if (i >= n) return 2*n - 2 - i;
    return i;
}

// prep: weights into MFMA B-fragment order (bf16). Verified layout (r4-r7).
__global__ __launch_bounds__(256) void prep(
    const float* __restrict__ wh, const float* __restrict__ wf,
    unsigned short* __restrict__ wtp, unsigned short* __restrict__ wfp)
{
    int i = blockIdx.x * 256 + threadIdx.x;   // 8192 groups
    if (i < 6144) {
        const int l = i & 63, r = i >> 6;
        const int ks = r % 6, r2 = r / 6;
        const int ot = r2 & 3, os = r2 >> 2;
        const int row = os*64 + ot*16 + (l & 15);
        const int k0  = ks*32 + (l >> 4)*8;
        ushort8 v;
        #pragma unroll
        for (int j = 0; j < 8; ++j) v[j] = f2b(wh[row*KF + k0 + j]);
        *(ushort8*)&wtp[(size_t)i * 8] = v;
    } else {
        const int g = i - 6144;               // 2048 groups
        const int l = g & 63, r = g >> 6;
        const int ks2 = r & 7, r2 = r >> 3;
        const int ct = r2 & 1, cs = r2 >> 1;
        const int c  = cs*32 + ct*16 + (l & 15);
        const int o0 = ks2*32 + (l >> 4)*8;
        ushort8 v;
        #pragma unroll
        for (int j = 0; j < 8; ++j) v[j] = f2b(wf[c*HID + o0 + j]);
        *(ushort8*)&wfp[(size_t)g * 8] = v;
    }
}

// prep2: conv weights -> bf16 [filter][tap][ch] (verified mapping r2-r7)
__global__ __launch_bounds__(256) void prep2(
    const float* __restrict__ w1, const float* __restrict__ w2,
    unsigned short* __restrict__ wcb)
{
    int i = blockIdx.x * 256 + threadIdx.x;
    if (i < 1152) {
        const int f = i / 576, rem = i - f * 576;
        const int t = rem >> 6, c = rem & 63;
        wcb[i] = f2b((f ? w2 : w1)[c*9 + t]);
    }
}

// SRCF: 0 = src is xin (64ch fp32 raw), 1 = src is bf16 state60 + aux
// DSTF: 0 = dst is bf16 state60 (+ write aux if SRCF==0), 1 = dst is out (64ch fp32)
template<int SRCF, int DSTF>
__global__ __launch_bounds__(256, 6) void nca_step(
    const float* __restrict__ xinf, const unsigned short* __restrict__ srcb,
    unsigned short* __restrict__ aux, void* __restrict__ dstv,
    const unsigned short* __restrict__ wtp, const unsigned short* __restrict__ wfp,
    const unsigned short* __restrict__ wcbg,
    const float* __restrict__ bh, const float* __restrict__ rnd)
{
    __shared__ __align__(16) char smem[SMEM_SZ];
    unsigned short* xs   = (unsigned short*)smem;
    char*           fch  = smem + OFF_FC;
    unsigned short* wcvb = (unsigned short*)(smem + OFF_WCV);
    float*          lgs  = (float*)(smem + OFF_LG);

    const int tid = threadIdx.x;
    // XCD slab decode: XCD x owns rows [x*256,(x+1)*256)
    const int d  = blockIdx.x;
    const int ii = d >> 3;
    const int R  = (d & 7) * 256 + (ii >> 2);   // global row index b*128+h
    const int w0 = (ii & 3) * TPX;
    const int h  = R & 127;
    const int b  = R >> 7;

    // ---- phase 1: conv weights (L2), life/gate, halo -> bf16 LDS ----
    for (int j = tid; j < 144; j += 256)
        ((ushort8*)wcvb)[j] = ((const ushort8*)wcbg)[j];
    if (tid < TPX) {
        const size_t pix = (size_t)R * WW + w0 + tid;
        float lf;
        if (SRCF == 0) lf = (xinf[pix*64] > 0.f) ? 1.f : 0.f;
        else           lf = (b2f(aux[pix*4]) > 0.f) ? 1.f : 0.f;
        lgs[tid]       = lf;
        lgs[TPX + tid] = (rnd[pix] > 0.5f) ? 1.f : 0.f;
    }
    const int q = tid & 3;
    for (int s0 = tid >> 2; s0 < 102; s0 += 64) {
        const int r3 = s0 / 34, wi = s0 - r3*34;
        const int sr = refl(h - 1 + r3, HH);
        const int sc = refl(w0 - 1 + wi, WW);
        const size_t pix = ((size_t)b*HH + sr)*WW + sc;
        ushort8 o0, o1;
        if (SRCF == 0) {
            const float* p = xinf + pix*64 + q*16;
            f4 a0 = *(const f4*)p, a1 = *(const f4*)(p+4);
            f4 a2 = *(const f4*)(p+8), a3 = *(const f4*)(p+12);
            o0[0]=f2b(a0.x); o0[1]=f2b(a0.y); o0[2]=f2b(a0.z); o0[3]=f2b(a0.w);
            o0[4]=f2b(a1.x); o0[5]=f2b(a1.y); o0[6]=f2b(a1.z); o0[7]=f2b(a1.w);
            o1[0]=f2b(a2.x); o1[1]=f2b(a2.y); o1[2]=f2b(a2.z); o1[3]=f2b(a2.w);
            o1[4]=f2b(a3.x); o1[5]=f2b(a3.y); o1[6]=f2b(a3.z); o1[7]=f2b(a3.w);
        } else if (q == 0) {
            const us4 av  = *(const us4*)(aux + pix*4);  // ch0..3
            const us4 s0v = *(const us4*)(srcb + pix*SC + 0);
            const us4 s1v = *(const us4*)(srcb + pix*SC + 4);
            const us4 s2v = *(const us4*)(srcb + pix*SC + 8);
            o0[0]=av[0]; o0[1]=av[1]; o0[2]=av[2]; o0[3]=av[3];
            o0[4]=s0v[0]; o0[5]=s0v[1]; o0[6]=s0v[2]; o0[7]=s0v[3];
            o1[0]=s1v[0]; o1[1]=s1v[1]; o1[2]=s1v[2]; o1[3]=s1v[3];
            o1[4]=s2v[0]; o1[5]=s2v[1]; o1[6]=s2v[2]; o1[7]=s2v[3];
        } else {
            const unsigned short* p = srcb + pix*SC + q*16 - 4;
            const us4 a0 = *(const us4*)(p + 0);
            const us4 a1 = *(const us4*)(p + 4);
            const us4 a2 = *(const us4*)(p + 8);
            const us4 a3 = *(const us4*)(p + 12);
            o0[0]=a0[0]; o0[1]=a0[1]; o0[2]=a0[2]; o0[3]=a0[3];
            o0[4]=a1[0]; o0[5]=a1[1]; o0[6]=a1[2]; o0[7]=a1[3];
            o1[0]=a2[0]; o1[1]=a2[1]; o1[2]=a2[2]; o1[3]=a2[3];
            o1[4]=a3[0]; o1[5]=a3[1]; o1[6]=a3[2]; o1[7]=a3[3];
        }
        unsigned short* dp = xs + (r3*34 + wi)*XSW + q*16;
        *(ushort8*)dp       = o0;
        *(ushort8*)(dp + 8) = o1;
    }
    __syncthreads();                                          // B1

    // ---- phase 2: conv features -> Fc (swizzled) ----
    {
        const int px = tid >> 3, cg = (tid & 7) * 8;
        float a1[8], a2[8];
        #pragma unroll
        for (int k = 0; k < 8; ++k) { a1[k] = 0.f; a2[k] = 0.f; }
        #pragma unroll
        for (int t = 0; t < 9; ++t) {             // t = i2*3 + j
            const int i2 = t / 3, j = t - 3*i2;
            const ushort8 xv  = *(const ushort8*)(xs + (j*34 + px + i2)*XSW + cg);
            const ushort8 wv1 = *(const ushort8*)(wcvb + t*64 + cg);
            const ushort8 wv2 = *(const ushort8*)(wcvb + 576 + t*64 + cg);
            #pragma unroll
            for (int k = 0; k < 8; ++k) {
                const float xf = b2f(xv[k]);
                a1[k] = fmaf(xf, b2f(wv1[k]), a1[k]);
                a2[k] = fmaf(xf, b2f(wv2[k]), a2[k]);
            }
        }
        ushort8 o1v, o2v;
        #pragma unroll
        for (int k = 0; k < 8; ++k) { o1v[k] = f2b(a1[k]); o2v[k] = f2b(a2[k]); }
        const int sw = (px & 7) << 4;
        *(ushort8*)(fch + ((px*256 + cg*2) ^ sw))       = o1v;
        *(ushort8*)(fch + ((px*256 + 128 + cg*2) ^ sw)) = o2v;
    }
    __syncthreads();                                          // B2

    // ---- phase 3: GEMM1 h = relu(F . Wh^T + b); wave = o-slice, tile 2Mt x 4Ot ----
    const int l = tid & 63, wv = tid >> 6;
    const int lr = l & 15, gq = l >> 4;
    const int os = wv;

    f4 acc[2][4];
    #pragma unroll
    for (int ot = 0; ot < 4; ++ot) {
        const float bv = bh[os*64 + ot*16 + lr];
        const f4 bvv = {bv, bv, bv, bv};
        acc[0][ot] = bvv; acc[1][ot] = bvv;
    }
    #pragma unroll
    for (int ks = 0; ks < 6; ++ks) {
        short8 afr[2];
        #pragma unroll
        for (int mt = 0; mt < 2; ++mt) {
            const int px = mt*16 + lr;
            if (ks < 2)    // x-features from halo center row
                afr[mt] = *(const short8*)(xs + (34 + px + 1)*XSW + ks*32 + gq*8);
            else
                afr[mt] = *(const short8*)(fch +
                            ((px*256 + (ks-2)*64 + gq*16) ^ ((px & 7) << 4)));
        }
        #pragma unroll
        for (int ot = 0; ot < 4; ++ot) {
            const short8 bfr = *(const short8*)(wtp + ((((os*4 + ot)*6 + ks)*64 + l) << 3));
            acc[0][ot] = __builtin_amdgcn_mfma_f32_16x16x32_bf16(afr[0], bfr, acc[0][ot], 0,0,0);
            acc[1][ot] = __builtin_amdgcn_mfma_f32_16x16x32_bf16(afr[1], bfr, acc[1][ot], 0,0,0);
        }
    }

    // epilogue base values from xs (still intact): bf16 state == carried base.
    // LDS reads cannot sink past the barrier, so no remat hazard (r7 lesson).
    const int mt2 = wv >> 1, cs = wv & 1;
    unsigned short baseb[8];
    #pragma unroll
    for (int ct = 0; ct < 2; ++ct)
      #pragma unroll
      for (int r2 = 0; r2 < 4; ++r2) {
        const int px = mt2*16 + gq*4 + r2;
        const int c  = cs*32 + ct*16 + lr;
        baseb[ct*4 + r2] = xs[(34 + px + 1)*XSW + c];
      }
    __syncthreads();                                          // B3 (xs/Fc reads done)

    // h (bf16, swizzled 512B rows) overlays xs
    #pragma unroll
    for (int mt = 0; mt < 2; ++mt)
      #pragma unroll
      for (int ot = 0; ot < 4; ++ot)
        #pragma unroll
        for (int r2 = 0; r2 < 4; ++r2) {
            const int px = mt*16 + gq*4 + r2;
            const int o  = os*64 + ot*16 + lr;
            *(unsigned short*)(smem + ((px*512 + o*2) ^ ((px & 7) << 4))) =
                f2b(fmaxf(acc[mt][ot][r2], 0.f));
        }
    __syncthreads();                                          // B4

    // ---- phase 4: GEMM2 dx = h . wf^T; wave = (px-half, c-half), tile 1x2 ----
    short8 ha[8];
    #pragma unroll
    for (int ks2 = 0; ks2 < 8; ++ks2) {
        const int px = mt2*16 + lr;
        ha[ks2] = *(const short8*)(smem + ((px*512 + ks2*64 + gq*16) ^ ((px & 7) << 4)));
    }
    __syncthreads();                                          // B5 (h region free)

    f4 acc2[2] = {{0.f,0.f,0.f,0.f},{0.f,0.f,0.f,0.f}};
    #pragma unroll
    for (int ks2 = 0; ks2 < 8; ++ks2) {
        #pragma unroll
        for (int ct = 0; ct < 2; ++ct) {
            const short8 bw = *(const short8*)(wfp + ((((cs*2 + ct)*8 + ks2)*64 + l) << 3));
            acc2[ct] = __builtin_amdgcn_mfma_f32_16x16x32_bf16(ha[ks2], bw, acc2[ct], 0,0,0);
        }
    }

    // ---- epilogue: gate + mask + life -> LDS stage ----
    unsigned short* stageB = (unsigned short*)smem;   // DSTF==0: [32][60] bf16
    float*          stageF = (float*)smem;            // DSTF==1: [32][64] fp32
    #pragma unroll
    for (int ct = 0; ct < 2; ++ct)
      #pragma unroll
      for (int r2 = 0; r2 < 4; ++r2) {
        const int px = mt2*16 + gq*4 + r2;
        const int c  = cs*32 + ct*16 + lr;
        const float life = lgs[px], g = lgs[TPX + px];
        const float base = b2f(baseb[ct*4 + r2]);
        const float dx   = acc2[ct][r2];
        if (DSTF == 1) {
            float outv;
            if (c >= 4) outv = (base + dx * g) * life;
            else {
                const size_t pix = (size_t)R * WW + w0 + px;
                outv = b2f(aux[pix*4 + c]) * life;
            }
            stageF[px*64 + c] = outv;
        } else {
            if (c >= 4)
                stageB[px*SC + (c-4)] = f2b((base + dx * g) * life);
            if (SRCF == 0 && c < 4) {
                const size_t pix = (size_t)R * WW + w0 + px;
                aux[pix*4 + c] = f2b(base * life);    // constant across steps
            }
        }
      }
    __syncthreads();                                          // B6

    // ---- coalesced full-line store ----
    const size_t pix0 = (size_t)R * WW + w0;
    if (DSTF == 1) {
        float* dstf = (float*)dstv + pix0 * 64;
        for (int i = tid; i < 512; i += 256)
            *(f4*)(dstf + i*4) = *(const f4*)(stageF + i*4);
    } else {
        unsigned short* dstb = (unsigned short*)dstv + pix0 * SC;
        if (tid < 240)
            *(ushort8*)(dstb + tid*8) = *(const ushort8*)(stageB + tid*8);
    }
}

extern "C" void kernel_launch(void* const* d_in, const int* in_sizes, int n_in,
                              void* d_out, int out_size, void* d_ws, size_t ws_size,
                              hipStream_t stream) {
    const float* xin = (const float*)d_in[0];
    const float* w1  = (const float*)d_in[1];
    const float* w2  = (const float*)d_in[2];
    const float* wh  = (const float*)d_in[3];
    const float* bh  = (const float*)d_in[4];
    const float* wf  = (const float*)d_in[5];
    const float* rv  = (const float*)d_in[6];

    unsigned short* wtp = (unsigned short*)((char*)d_ws + WS_WTP);
    unsigned short* wfp = (unsigned short*)((char*)d_ws + WS_WFP);
    unsigned short* wcb = (unsigned short*)((char*)d_ws + WS_WCB);
    unsigned short* aux = (unsigned short*)((char*)d_ws + WS_AUX);
    unsigned short* stb = (unsigned short*)((char*)d_ws + WS_ST);   // bf16 state A
    unsigned short* omb = (unsigned short*)d_out;                   // bf16 state B (scratch)

    prep <<<dim3(32), dim3(256), 0, stream>>>(wh, wf, wtp, wfp);
    prep2<<<dim3(5),  dim3(256), 0, stream>>>(w1, w2, wcb);

    dim3 g(8192), blk(256);
    nca_step<0,0><<<g, blk, 0, stream>>>(xin, nullptr, aux, stb, wtp, wfp, wcb, bh, rv);
    for (int s = 1; s < 7; ++s) {
        const unsigned short* sp = (s & 1) ? stb : omb;
        unsigned short* dp       = (s & 1) ? omb : stb;
        nca_step<1,0><<<g, blk, 0, stream>>>(nullptr, sp, aux, dp, wtp, wfp, wcb, bh,
                                             rv + (size_t)s * NPIX);
    }
    nca_step<1,1><<<g, blk, 0, stream>>>(nullptr, stb, aux, d_out, wtp, wfp, wcb, bh,
                                         rv + (size_t)7 * NPIX);
}